// Round 1
// baseline (239.428 us; speedup 1.0000x reference)
//
#include <hip/hip_runtime.h>
#include <stdint.h>

#define D_DIM 512
#define B_ROWS 1024
#define C_ROWS 32768

typedef __attribute__((ext_vector_type(8))) short short8;
typedef __attribute__((ext_vector_type(4))) float floatx4;

#define GLOBAL_AS __attribute__((address_space(1)))
#define LDS_AS __attribute__((address_space(3)))

// fp32 -> bf16 round-to-nearest-even (inputs are well-behaved, no NaN path)
__device__ inline unsigned short f2bf(float f) {
    unsigned u = __float_as_uint(f);
    u += 0x7fffu + ((u >> 16) & 1u);
    return (unsigned short)(u >> 16);
}

__device__ inline void async_copy16(const unsigned short* g, unsigned short* l) {
    __builtin_amdgcn_global_load_lds((const GLOBAL_AS void*)g, (LDS_AS void*)l, 16, 0, 0);
}

// Normalize rows to norm 3, emit bf16. One wave per row (lane i handles 8 floats).
__global__ void norm_rows_kernel(const float* __restrict__ src,
                                 unsigned short* __restrict__ dst, int nrows) {
    const int wid = threadIdx.x >> 6;
    const int lane = threadIdx.x & 63;
    const int row = blockIdx.x * 4 + wid;
    if (row >= nrows) return;

    const float4* p = (const float4*)(src + (size_t)row * D_DIM + lane * 8);
    float4 v0 = p[0];
    float4 v1 = p[1];
    float ss = v0.x * v0.x + v0.y * v0.y + v0.z * v0.z + v0.w * v0.w +
               v1.x * v1.x + v1.y * v1.y + v1.z * v1.z + v1.w * v1.w;
#pragma unroll
    for (int off = 1; off < 64; off <<= 1) ss += __shfl_xor(ss, off);
    // norms are ~2.8..23 here, far above the 1e-12 eps in the reference
    const float s = 3.0f * rsqrtf(ss);

    unsigned short h[8];
    h[0] = f2bf(v0.x * s); h[1] = f2bf(v0.y * s);
    h[2] = f2bf(v0.z * s); h[3] = f2bf(v0.w * s);
    h[4] = f2bf(v1.x * s); h[5] = f2bf(v1.y * s);
    h[6] = f2bf(v1.z * s); h[7] = f2bf(v1.w * s);
    uint4 packed;
    packed.x = (unsigned)h[0] | ((unsigned)h[1] << 16);
    packed.y = (unsigned)h[2] | ((unsigned)h[3] << 16);
    packed.z = (unsigned)h[4] | ((unsigned)h[5] << 16);
    packed.w = (unsigned)h[6] | ((unsigned)h[7] << 16);
    *(uint4*)(dst + (size_t)row * D_DIM + lane * 8) = packed;
}

// 128x128 tile bf16 MFMA GEMM over K=512, fused exp(2*s) row-sum epilogue.
// A: [1024,512] bf16 row-major; Bm: [32768,512] bf16 row-major (i.e. B^T).
__global__ void __launch_bounds__(256)
gemm_lse_kernel(const unsigned short* __restrict__ A,
                const unsigned short* __restrict__ Bm,
                float* __restrict__ rowsum) {
    __shared__ unsigned short sA[128 * 32];  // 8 KB, row-major, no pad (global_load_lds)
    __shared__ unsigned short sB[128 * 32];  // 8 KB

    const int tid = threadIdx.x;
    const int wid = tid >> 6;
    const int lane = tid & 63;
    const int m0 = blockIdx.y * 128;
    const int n0 = blockIdx.x * 128;

    // Staging map: wave w round j covers rows [j*64 + w*16, +16), lane i -> base + i*16B
    const int srow = wid * 16 + (lane >> 2);      // 0..63
    const int skoff = (lane & 3) * 8;             // bf16 elements within 32-K row
    const unsigned short* gA0 = A + (size_t)(m0 + srow) * D_DIM + skoff;
    const unsigned short* gA1 = gA0 + (size_t)64 * D_DIM;
    const unsigned short* gB0 = Bm + (size_t)(n0 + srow) * D_DIM + skoff;
    const unsigned short* gB1 = gB0 + (size_t)64 * D_DIM;
    unsigned short* lA0 = &sA[srow * 32 + skoff];
    unsigned short* lA1 = lA0 + 64 * 32;
    unsigned short* lB0 = &sB[srow * 32 + skoff];
    unsigned short* lB1 = lB0 + 64 * 32;

    // 2x2 wave arrangement, each wave owns 64x64 via 4x4 MFMA 16x16x32 tiles
    const int wm = (wid >> 1) * 64;
    const int wn = (wid & 1) * 64;
    const int fr = lane & 15;        // A-row / B-col within 16-tile
    const int fk = (lane >> 4) * 8;  // K offset of this lane's 8 elements
    const int quad = lane >> 4;

    floatx4 acc[4][4];
    const floatx4 zero = {0.f, 0.f, 0.f, 0.f};
#pragma unroll
    for (int i = 0; i < 4; ++i)
#pragma unroll
        for (int j = 0; j < 4; ++j) acc[i][j] = zero;

    for (int kk = 0; kk < D_DIM; kk += 32) {
        async_copy16(gA0 + kk, lA0);
        async_copy16(gA1 + kk, lA1);
        async_copy16(gB0 + kk, lB0);
        async_copy16(gB1 + kk, lB1);
        __syncthreads();  // drains vmcnt(0) before barrier -> LDS tiles visible

        short8 af[4], bfv[4];
#pragma unroll
        for (int t = 0; t < 4; ++t) {
            af[t]  = *(const short8*)&sA[(wm + t * 16 + fr) * 32 + fk];
            bfv[t] = *(const short8*)&sB[(wn + t * 16 + fr) * 32 + fk];
        }
#pragma unroll
        for (int ti = 0; ti < 4; ++ti)
#pragma unroll
            for (int tj = 0; tj < 4; ++tj)
                acc[ti][tj] = __builtin_amdgcn_mfma_f32_16x16x32_bf16(
                    af[ti], bfv[tj], acc[ti][tj], 0, 0, 0);
        __syncthreads();  // protect LDS before next stage overwrites
    }

    // Epilogue: rowsum[m] += sum_n exp(2*S[m][n]) over this block's 128 cols.
    // C/D layout: col = lane&15, row = quad*4 + reg  [m89/m91-verified]
#pragma unroll
    for (int ti = 0; ti < 4; ++ti) {
        float rs[4] = {0.f, 0.f, 0.f, 0.f};
#pragma unroll
        for (int tj = 0; tj < 4; ++tj)
#pragma unroll
            for (int r = 0; r < 4; ++r)
                rs[r] += __expf(2.0f * acc[ti][tj][r]);
        // sum across the 16 col-lanes (bits 0..3 of lane)
#pragma unroll
        for (int r = 0; r < 4; ++r) {
            rs[r] += __shfl_xor(rs[r], 1);
            rs[r] += __shfl_xor(rs[r], 2);
            rs[r] += __shfl_xor(rs[r], 4);
            rs[r] += __shfl_xor(rs[r], 8);
        }
        if (fr == 0) {
#pragma unroll
            for (int r = 0; r < 4; ++r)
                atomicAdd(&rowsum[m0 + wm + ti * 16 + quad * 4 + r], rs[r]);
        }
    }
}

// pos2[b] = 2 * dot(batch[b], P[labels[b]]) from the bf16 normalized arrays.
__global__ void pos_dot_kernel(const unsigned short* __restrict__ A,
                               const unsigned short* __restrict__ Bm,
                               const int* __restrict__ labels,
                               float* __restrict__ pos2) {
    const int wid = threadIdx.x >> 6;
    const int lane = threadIdx.x & 63;
    const int b = blockIdx.x * 4 + wid;
    if (b >= B_ROWS) return;
    const int l = labels[b];

    uint4 ua = *(const uint4*)(A + (size_t)b * D_DIM + lane * 8);
    uint4 ub = *(const uint4*)(Bm + (size_t)l * D_DIM + lane * 8);
    const unsigned* au = (const unsigned*)&ua;
    const unsigned* bu = (const unsigned*)&ub;
    float s = 0.f;
#pragma unroll
    for (int j = 0; j < 4; ++j) {
        float a0 = __uint_as_float(au[j] << 16);
        float a1 = __uint_as_float(au[j] & 0xffff0000u);
        float b0 = __uint_as_float(bu[j] << 16);
        float b1 = __uint_as_float(bu[j] & 0xffff0000u);
        s += a0 * b0 + a1 * b1;
    }
#pragma unroll
    for (int off = 1; off < 64; off <<= 1) s += __shfl_xor(s, off);
    if (lane == 0) pos2[b] = 2.0f * s;
}

__global__ void finalize_kernel(const float* __restrict__ rowsum,
                                const float* __restrict__ pos2,
                                float* __restrict__ out) {
    __shared__ float red[4];
    const int tid = threadIdx.x;
    float local = 0.f;
    for (int b = tid; b < B_ROWS; b += 256) {
        float p2 = pos2[b];
        float sneg = rowsum[b] - __expf(p2);  // mask out the positive class
        local += logf(sneg) - p2;
    }
#pragma unroll
    for (int off = 1; off < 64; off <<= 1) local += __shfl_xor(local, off);
    const int wid = tid >> 6;
    const int lane = tid & 63;
    if (lane == 0) red[wid] = local;
    __syncthreads();
    if (tid == 0) {
        out[0] = (red[0] + red[1] + red[2] + red[3]) / (float)B_ROWS;
    }
}

extern "C" void kernel_launch(void* const* d_in, const int* in_sizes, int n_in,
                              void* d_out, int out_size, void* d_ws, size_t ws_size,
                              hipStream_t stream) {
    const float* emb = (const float*)d_in[0];    // [1024, 512]
    const float* prox = (const float*)d_in[1];   // [32768, 512]
    const int* labels = (const int*)d_in[2];     // [1024]
    float* out = (float*)d_out;

    char* ws = (char*)d_ws;
    unsigned short* Pbf = (unsigned short*)ws;                               // 32 MB
    unsigned short* Abf = (unsigned short*)(ws + (size_t)C_ROWS * D_DIM * 2);  // 1 MB
    float* rowsum = (float*)(ws + (size_t)C_ROWS * D_DIM * 2 + (size_t)B_ROWS * D_DIM * 2);
    float* pos2 = rowsum + B_ROWS;

    hipMemsetAsync(rowsum, 0, B_ROWS * sizeof(float), stream);
    norm_rows_kernel<<<C_ROWS / 4, 256, 0, stream>>>(prox, Pbf, C_ROWS);
    norm_rows_kernel<<<B_ROWS / 4, 256, 0, stream>>>(emb, Abf, B_ROWS);
    gemm_lse_kernel<<<dim3(C_ROWS / 128, B_ROWS / 128), 256, 0, stream>>>(Abf, Pbf, rowsum);
    pos_dot_kernel<<<B_ROWS / 4, 256, 0, stream>>>(Abf, Pbf, labels, pos2);
    finalize_kernel<<<1, 256, 0, stream>>>(rowsum, pos2, out);
}

// Round 2
// 155.649 us; speedup vs baseline: 1.5383x; 1.5383x over previous
//
#include <hip/hip_runtime.h>
#include <stdint.h>

#define D_DIM 512
#define B_ROWS 1024
#define C_ROWS 32768
#define NBLK (C_ROWS / 128)   // 256 n-blocks

typedef __attribute__((ext_vector_type(8))) short short8;
typedef __attribute__((ext_vector_type(4))) float floatx4;

#define GLOBAL_AS __attribute__((address_space(1)))
#define LDS_AS __attribute__((address_space(3)))

// fp32 -> bf16 round-to-nearest-even (inputs are well-behaved, no NaN path)
__device__ inline unsigned short f2bf(float f) {
    unsigned u = __float_as_uint(f);
    u += 0x7fffu + ((u >> 16) & 1u);
    return (unsigned short)(u >> 16);
}

__device__ inline void async_copy16(const unsigned short* g, unsigned short* l) {
    __builtin_amdgcn_global_load_lds((const GLOBAL_AS void*)g, (LDS_AS void*)l, 16, 0, 0);
}

// Normalize rows to norm 3, emit bf16. One wave per row (lane i handles 8 floats).
__global__ void norm_rows_kernel(const float* __restrict__ src,
                                 unsigned short* __restrict__ dst, int nrows) {
    const int wid = threadIdx.x >> 6;
    const int lane = threadIdx.x & 63;
    const int row = blockIdx.x * 4 + wid;
    if (row >= nrows) return;

    const float4* p = (const float4*)(src + (size_t)row * D_DIM + lane * 8);
    float4 v0 = p[0];
    float4 v1 = p[1];
    float ss = v0.x * v0.x + v0.y * v0.y + v0.z * v0.z + v0.w * v0.w +
               v1.x * v1.x + v1.y * v1.y + v1.z * v1.z + v1.w * v1.w;
#pragma unroll
    for (int off = 1; off < 64; off <<= 1) ss += __shfl_xor(ss, off);
    // norms are ~2.8..23 here, far above the 1e-12 eps in the reference
    const float s = 3.0f * rsqrtf(ss);

    unsigned short h[8];
    h[0] = f2bf(v0.x * s); h[1] = f2bf(v0.y * s);
    h[2] = f2bf(v0.z * s); h[3] = f2bf(v0.w * s);
    h[4] = f2bf(v1.x * s); h[5] = f2bf(v1.y * s);
    h[6] = f2bf(v1.z * s); h[7] = f2bf(v1.w * s);
    uint4 packed;
    packed.x = (unsigned)h[0] | ((unsigned)h[1] << 16);
    packed.y = (unsigned)h[2] | ((unsigned)h[3] << 16);
    packed.z = (unsigned)h[4] | ((unsigned)h[5] << 16);
    packed.w = (unsigned)h[6] | ((unsigned)h[7] << 16);
    *(uint4*)(dst + (size_t)row * D_DIM + lane * 8) = packed;
}

// 128x128 tile bf16 MFMA GEMM over K=512, BK=64 staged as two 32-wide chunks
// (halves barrier-drain count vs BK=32), fused exp(2*s) row-sum epilogue.
// Writes per-block partial row sums to part[m][nblk] (no global atomics).
__global__ void __launch_bounds__(256)
gemm_lse_kernel(const unsigned short* __restrict__ A,
                const unsigned short* __restrict__ Bm,
                float* __restrict__ part) {
    __shared__ unsigned short sA[2][128 * 32];  // 2 chunks x 8 KB
    __shared__ unsigned short sB[2][128 * 32];
    __shared__ float red[128];

    const int tid = threadIdx.x;
    const int wid = tid >> 6;
    const int lane = tid & 63;
    const int m0 = blockIdx.y * 128;
    const int n0 = blockIdx.x * 128;

    if (tid < 128) red[tid] = 0.f;

    // Staging map: lds byte offset == wave_base + lane*16 (global_load_lds rule)
    const int srow = wid * 16 + (lane >> 2);      // 0..63
    const int skoff = (lane & 3) * 8;             // bf16 elements within 32-K chunk
    const unsigned short* gA = A + (size_t)(m0 + srow) * D_DIM + skoff;
    const unsigned short* gB = Bm + (size_t)(n0 + srow) * D_DIM + skoff;
    const int loff = srow * 32 + skoff;

    // 2x2 wave arrangement, each wave owns 64x64 via 4x4 MFMA 16x16x32 tiles
    const int wm = (wid >> 1) * 64;
    const int wn = (wid & 1) * 64;
    const int fr = lane & 15;        // A-row / B-col within 16-tile
    const int fk = (lane >> 4) * 8;  // K offset of this lane's 8 elements
    const int quad = lane >> 4;

    floatx4 acc[4][4];
    const floatx4 zero = {0.f, 0.f, 0.f, 0.f};
#pragma unroll
    for (int i = 0; i < 4; ++i)
#pragma unroll
        for (int j = 0; j < 4; ++j) acc[i][j] = zero;

    for (int kk = 0; kk < D_DIM; kk += 64) {
        // chunk 0: k in [kk, kk+32); chunk 1: k in [kk+32, kk+64)
        async_copy16(gA + kk,                  &sA[0][loff]);
        async_copy16(gA + kk + 64 * D_DIM,     &sA[0][loff + 64 * 32]);
        async_copy16(gA + kk + 32,             &sA[1][loff]);
        async_copy16(gA + kk + 32 + 64 * D_DIM, &sA[1][loff + 64 * 32]);
        async_copy16(gB + kk,                  &sB[0][loff]);
        async_copy16(gB + kk + 64 * D_DIM,     &sB[0][loff + 64 * 32]);
        async_copy16(gB + kk + 32,             &sB[1][loff]);
        async_copy16(gB + kk + 32 + 64 * D_DIM, &sB[1][loff + 64 * 32]);
        __syncthreads();  // drains vmcnt(0) -> both chunks visible

#pragma unroll
        for (int c = 0; c < 2; ++c) {
            short8 af[4], bfv[4];
#pragma unroll
            for (int t = 0; t < 4; ++t) {
                af[t]  = *(const short8*)&sA[c][(wm + t * 16 + fr) * 32 + fk];
                bfv[t] = *(const short8*)&sB[c][(wn + t * 16 + fr) * 32 + fk];
            }
#pragma unroll
            for (int ti = 0; ti < 4; ++ti)
#pragma unroll
                for (int tj = 0; tj < 4; ++tj)
                    acc[ti][tj] = __builtin_amdgcn_mfma_f32_16x16x32_bf16(
                        af[ti], bfv[tj], acc[ti][tj], 0, 0, 0);
        }
        __syncthreads();  // protect LDS before next stage overwrites
    }

    // Epilogue: red[m_local] += sum over this block's 128 cols of exp(2*S).
    // C/D layout: col = lane&15, row = quad*4 + reg  [m89/m91-verified]
#pragma unroll
    for (int ti = 0; ti < 4; ++ti) {
        float rs[4] = {0.f, 0.f, 0.f, 0.f};
#pragma unroll
        for (int tj = 0; tj < 4; ++tj)
#pragma unroll
            for (int r = 0; r < 4; ++r)
                rs[r] += __expf(2.0f * acc[ti][tj][r]);
        // sum across the 16 col-lanes (bits 0..3 of lane)
#pragma unroll
        for (int r = 0; r < 4; ++r) {
            rs[r] += __shfl_xor(rs[r], 1);
            rs[r] += __shfl_xor(rs[r], 2);
            rs[r] += __shfl_xor(rs[r], 4);
            rs[r] += __shfl_xor(rs[r], 8);
        }
        if (fr == 0) {
#pragma unroll
            for (int r = 0; r < 4; ++r)
                atomicAdd(&red[wm + ti * 16 + quad * 4 + r], rs[r]);  // LDS atomic
        }
    }
    __syncthreads();
    if (tid < 128) part[(size_t)(m0 + tid) * NBLK + blockIdx.x] = red[tid];
}

// Per-row: sum the 256 partials, compute positive dot, emit per-row loss.
__global__ void rowloss_kernel(const float* __restrict__ part,
                               const unsigned short* __restrict__ A,
                               const unsigned short* __restrict__ Bm,
                               const int* __restrict__ labels,
                               float* __restrict__ rowloss) {
    const int wid = threadIdx.x >> 6;
    const int lane = threadIdx.x & 63;
    const int b = blockIdx.x * 4 + wid;
    if (b >= B_ROWS) return;

    // 256 partials per row, 4 per lane, coalesced float4
    float4 pv = *(const float4*)&part[(size_t)b * NBLK + lane * 4];
    float s = pv.x + pv.y + pv.z + pv.w;

    // positive dot from the bf16 normalized arrays
    const int l = labels[b];
    uint4 ua = *(const uint4*)(A + (size_t)b * D_DIM + lane * 8);
    uint4 ub = *(const uint4*)(Bm + (size_t)l * D_DIM + lane * 8);
    const unsigned* au = (const unsigned*)&ua;
    const unsigned* bu = (const unsigned*)&ub;
    float d = 0.f;
#pragma unroll
    for (int j = 0; j < 4; ++j) {
        float a0 = __uint_as_float(au[j] << 16);
        float a1 = __uint_as_float(au[j] & 0xffff0000u);
        float b0 = __uint_as_float(bu[j] << 16);
        float b1 = __uint_as_float(bu[j] & 0xffff0000u);
        d += a0 * b0 + a1 * b1;
    }
#pragma unroll
    for (int off = 1; off < 64; off <<= 1) {
        s += __shfl_xor(s, off);
        d += __shfl_xor(d, off);
    }
    if (lane == 0) {
        float p2 = 2.0f * d;
        rowloss[b] = logf(s - __expf(p2)) - p2;  // mask positive class
    }
}

__global__ void finalize_kernel(const float* __restrict__ rowloss,
                                float* __restrict__ out) {
    __shared__ float red[4];
    const int tid = threadIdx.x;
    float local = 0.f;
    for (int b = tid; b < B_ROWS; b += 256) local += rowloss[b];
#pragma unroll
    for (int off = 1; off < 64; off <<= 1) local += __shfl_xor(local, off);
    const int wid = tid >> 6;
    const int lane = tid & 63;
    if (lane == 0) red[wid] = local;
    __syncthreads();
    if (tid == 0) out[0] = (red[0] + red[1] + red[2] + red[3]) / (float)B_ROWS;
}

extern "C" void kernel_launch(void* const* d_in, const int* in_sizes, int n_in,
                              void* d_out, int out_size, void* d_ws, size_t ws_size,
                              hipStream_t stream) {
    const float* emb = (const float*)d_in[0];    // [1024, 512]
    const float* prox = (const float*)d_in[1];   // [32768, 512]
    const int* labels = (const int*)d_in[2];     // [1024]
    float* out = (float*)d_out;

    char* ws = (char*)d_ws;
    unsigned short* Pbf = (unsigned short*)ws;                                 // 32 MB
    unsigned short* Abf = (unsigned short*)(ws + (size_t)C_ROWS * D_DIM * 2);  // 1 MB
    float* part = (float*)(ws + (size_t)C_ROWS * D_DIM * 2 + (size_t)B_ROWS * D_DIM * 2);  // 1 MB
    float* rowloss = part + (size_t)B_ROWS * NBLK;                             // 4 KB

    norm_rows_kernel<<<C_ROWS / 4, 256, 0, stream>>>(prox, Pbf, C_ROWS);
    norm_rows_kernel<<<B_ROWS / 4, 256, 0, stream>>>(emb, Abf, B_ROWS);
    gemm_lse_kernel<<<dim3(NBLK, B_ROWS / 128), 256, 0, stream>>>(Abf, Pbf, part);
    rowloss_kernel<<<B_ROWS / 4, 256, 0, stream>>>(part, Abf, Pbf, labels, rowloss);
    finalize_kernel<<<1, 256, 0, stream>>>(rowloss, out);
}

// Round 3
// 153.360 us; speedup vs baseline: 1.5612x; 1.0149x over previous
//
#include <hip/hip_runtime.h>
#include <stdint.h>

#define D_DIM 512
#define B_ROWS 1024
#define C_ROWS 32768
#define NBLK (C_ROWS / 128)   // 256 n-blocks

typedef __attribute__((ext_vector_type(8))) short short8;
typedef __attribute__((ext_vector_type(4))) float floatx4;

#define GLOBAL_AS __attribute__((address_space(1)))
#define LDS_AS __attribute__((address_space(3)))

// fp32 -> bf16 round-to-nearest-even (inputs are well-behaved, no NaN path)
__device__ inline unsigned short f2bf(float f) {
    unsigned u = __float_as_uint(f);
    u += 0x7fffu + ((u >> 16) & 1u);
    return (unsigned short)(u >> 16);
}

__device__ inline void async_copy16(const unsigned short* g, unsigned short* l) {
    __builtin_amdgcn_global_load_lds((const GLOBAL_AS void*)g, (LDS_AS void*)l, 16, 0, 0);
}

// Normalize rows of BOTH inputs to norm 3, emit bf16. One wave per row.
// Rows [0, C_ROWS) -> proxies, rows [C_ROWS, C_ROWS+B_ROWS) -> embeddings.
__global__ void norm_rows_kernel(const float* __restrict__ prox,
                                 const float* __restrict__ emb,
                                 unsigned short* __restrict__ Pbf,
                                 unsigned short* __restrict__ Abf) {
    const int wid = threadIdx.x >> 6;
    const int lane = threadIdx.x & 63;
    int row = blockIdx.x * 4 + wid;
    const float* src;
    unsigned short* dst;
    if (row < C_ROWS) {
        src = prox; dst = Pbf;
    } else {
        row -= C_ROWS;
        src = emb; dst = Abf;
    }

    const float4* p = (const float4*)(src + (size_t)row * D_DIM + lane * 8);
    float4 v0 = p[0];
    float4 v1 = p[1];
    float ss = v0.x * v0.x + v0.y * v0.y + v0.z * v0.z + v0.w * v0.w +
               v1.x * v1.x + v1.y * v1.y + v1.z * v1.z + v1.w * v1.w;
#pragma unroll
    for (int off = 1; off < 64; off <<= 1) ss += __shfl_xor(ss, off);
    // norms are ~2.8..23 here, far above the 1e-12 eps in the reference
    const float s = 3.0f * rsqrtf(ss);

    unsigned short h[8];
    h[0] = f2bf(v0.x * s); h[1] = f2bf(v0.y * s);
    h[2] = f2bf(v0.z * s); h[3] = f2bf(v0.w * s);
    h[4] = f2bf(v1.x * s); h[5] = f2bf(v1.y * s);
    h[6] = f2bf(v1.z * s); h[7] = f2bf(v1.w * s);
    uint4 packed;
    packed.x = (unsigned)h[0] | ((unsigned)h[1] << 16);
    packed.y = (unsigned)h[2] | ((unsigned)h[3] << 16);
    packed.z = (unsigned)h[4] | ((unsigned)h[5] << 16);
    packed.w = (unsigned)h[6] | ((unsigned)h[7] << 16);
    *(uint4*)(dst + (size_t)row * D_DIM + lane * 8) = packed;
}

// 128x128 tile bf16 MFMA GEMM over K=512, BK=64 staged as two 32-wide chunks,
// fused exp(2*s) row-sum epilogue. LDS granule-swizzled to kill the 8-way
// ds_read_b128 bank conflict: logical granule g of row r lives at physical
// granule (g + (r>>1)) & 3 (16B granules within the 64B row).
// Writes per-block partial row sums to part[m][nblk] (no global atomics).
__global__ void __launch_bounds__(256)
gemm_lse_kernel(const unsigned short* __restrict__ A,
                const unsigned short* __restrict__ Bm,
                float* __restrict__ part) {
    __shared__ unsigned short sA[2][128 * 32];  // 2 chunks x 8 KB
    __shared__ unsigned short sB[2][128 * 32];
    __shared__ float red[128];

    const int tid = threadIdx.x;
    const int wid = tid >> 6;
    const int lane = tid & 63;
    const int m0 = blockIdx.x * 128;   // m-fastest: consecutive blocks share B-tile
    const int n0 = blockIdx.y * 128;

    if (tid < 128) red[tid] = 0.f;

    // Staging: HW writes lane's 16B at wave_base + lane*16 == srow*64B + sg*16B.
    // Under the swizzle, that physical slot holds LOGICAL granule
    // gl = (sg - (srow>>1)) & 3, so the lane fetches that granule from global.
    const int srow = wid * 16 + (lane >> 2);                 // 0..63
    const int sg = lane & 3;                                 // physical granule
    const int gl = (sg - ((lane >> 3) & 3)) & 3;             // (srow>>1)&3 == (lane>>3)&3
    const unsigned short* gA = A + (size_t)(m0 + srow) * D_DIM + gl * 8;
    const unsigned short* gB = Bm + (size_t)(n0 + srow) * D_DIM + gl * 8;
    const int loff = srow * 32 + sg * 8;                     // ushort units

    // 2x2 wave arrangement, each wave owns 64x64 via 4x4 MFMA 16x16x32 tiles
    const int wm = (wid >> 1) * 64;
    const int wn = (wid & 1) * 64;
    const int fr = lane & 15;        // A-row / B-col within 16-tile
    const int quad = lane >> 4;      // logical K-granule of this lane's fragment
    // physical granule for fragment reads: (quad + (row>>1))&3; row's low bits
    // below 16-tile granularity come only from fr (wm, t*16 are ≡0 mod 4 after >>1)
    const int swz = (((quad + ((fr >> 1) & 3)) & 3) * 8);

    floatx4 acc[4][4];
    const floatx4 zero = {0.f, 0.f, 0.f, 0.f};
#pragma unroll
    for (int i = 0; i < 4; ++i)
#pragma unroll
        for (int j = 0; j < 4; ++j) acc[i][j] = zero;

    for (int kk = 0; kk < D_DIM; kk += 64) {
        // chunk 0: k in [kk, kk+32); chunk 1: k in [kk+32, kk+64)
        async_copy16(gA + kk,                   &sA[0][loff]);
        async_copy16(gA + kk + 64 * D_DIM,      &sA[0][loff + 64 * 32]);
        async_copy16(gA + kk + 32,              &sA[1][loff]);
        async_copy16(gA + kk + 32 + 64 * D_DIM, &sA[1][loff + 64 * 32]);
        async_copy16(gB + kk,                   &sB[0][loff]);
        async_copy16(gB + kk + 64 * D_DIM,      &sB[0][loff + 64 * 32]);
        async_copy16(gB + kk + 32,              &sB[1][loff]);
        async_copy16(gB + kk + 32 + 64 * D_DIM, &sB[1][loff + 64 * 32]);
        __syncthreads();  // drains vmcnt(0) -> both chunks visible

#pragma unroll
        for (int c = 0; c < 2; ++c) {
            short8 af[4], bfv[4];
#pragma unroll
            for (int t = 0; t < 4; ++t) {
                af[t]  = *(const short8*)&sA[c][(wm + t * 16 + fr) * 32 + swz];
                bfv[t] = *(const short8*)&sB[c][(wn + t * 16 + fr) * 32 + swz];
            }
#pragma unroll
            for (int ti = 0; ti < 4; ++ti)
#pragma unroll
                for (int tj = 0; tj < 4; ++tj)
                    acc[ti][tj] = __builtin_amdgcn_mfma_f32_16x16x32_bf16(
                        af[ti], bfv[tj], acc[ti][tj], 0, 0, 0);
        }
        __syncthreads();  // protect LDS before next stage overwrites
    }

    // Epilogue: red[m_local] += sum over this block's 128 cols of exp(2*S).
    // C/D layout: col = lane&15, row = quad*4 + reg  [m89/m91-verified]
#pragma unroll
    for (int ti = 0; ti < 4; ++ti) {
        float rs[4] = {0.f, 0.f, 0.f, 0.f};
#pragma unroll
        for (int tj = 0; tj < 4; ++tj)
#pragma unroll
            for (int r = 0; r < 4; ++r)
                rs[r] += __expf(2.0f * acc[ti][tj][r]);
        // sum across the 16 col-lanes (bits 0..3 of lane)
#pragma unroll
        for (int r = 0; r < 4; ++r) {
            rs[r] += __shfl_xor(rs[r], 1);
            rs[r] += __shfl_xor(rs[r], 2);
            rs[r] += __shfl_xor(rs[r], 4);
            rs[r] += __shfl_xor(rs[r], 8);
        }
        if (fr == 0) {
#pragma unroll
            for (int r = 0; r < 4; ++r)
                atomicAdd(&red[wm + ti * 16 + quad * 4 + r], rs[r]);  // LDS atomic
        }
    }
    __syncthreads();
    if (tid < 128) part[(size_t)(m0 + tid) * NBLK + blockIdx.y] = red[tid];
}

// Per-row: sum the 256 partials, compute positive dot, emit per-row loss.
__global__ void rowloss_kernel(const float* __restrict__ part,
                               const unsigned short* __restrict__ A,
                               const unsigned short* __restrict__ Bm,
                               const int* __restrict__ labels,
                               float* __restrict__ rowloss) {
    const int wid = threadIdx.x >> 6;
    const int lane = threadIdx.x & 63;
    const int b = blockIdx.x * 4 + wid;
    if (b >= B_ROWS) return;

    // 256 partials per row, 4 per lane, coalesced float4
    float4 pv = *(const float4*)&part[(size_t)b * NBLK + lane * 4];
    float s = pv.x + pv.y + pv.z + pv.w;

    // positive dot from the bf16 normalized arrays
    const int l = labels[b];
    uint4 ua = *(const uint4*)(A + (size_t)b * D_DIM + lane * 8);
    uint4 ub = *(const uint4*)(Bm + (size_t)l * D_DIM + lane * 8);
    const unsigned* au = (const unsigned*)&ua;
    const unsigned* bu = (const unsigned*)&ub;
    float d = 0.f;
#pragma unroll
    for (int j = 0; j < 4; ++j) {
        float a0 = __uint_as_float(au[j] << 16);
        float a1 = __uint_as_float(au[j] & 0xffff0000u);
        float b0 = __uint_as_float(bu[j] << 16);
        float b1 = __uint_as_float(bu[j] & 0xffff0000u);
        d += a0 * b0 + a1 * b1;
    }
#pragma unroll
    for (int off = 1; off < 64; off <<= 1) {
        s += __shfl_xor(s, off);
        d += __shfl_xor(d, off);
    }
    if (lane == 0) {
        float p2 = 2.0f * d;
        rowloss[b] = logf(s - __expf(p2)) - p2;  // mask positive class
    }
}

__global__ void finalize_kernel(const float* __restrict__ rowloss,
                                float* __restrict__ out) {
    __shared__ float red[4];
    const int tid = threadIdx.x;
    float local = 0.f;
    for (int b = tid; b < B_ROWS; b += 256) local += rowloss[b];
#pragma unroll
    for (int off = 1; off < 64; off <<= 1) local += __shfl_xor(local, off);
    const int wid = tid >> 6;
    const int lane = tid & 63;
    if (lane == 0) red[wid] = local;
    __syncthreads();
    if (tid == 0) out[0] = (red[0] + red[1] + red[2] + red[3]) / (float)B_ROWS;
}

extern "C" void kernel_launch(void* const* d_in, const int* in_sizes, int n_in,
                              void* d_out, int out_size, void* d_ws, size_t ws_size,
                              hipStream_t stream) {
    const float* emb = (const float*)d_in[0];    // [1024, 512]
    const float* prox = (const float*)d_in[1];   // [32768, 512]
    const int* labels = (const int*)d_in[2];     // [1024]
    float* out = (float*)d_out;

    char* ws = (char*)d_ws;
    unsigned short* Pbf = (unsigned short*)ws;                                 // 32 MB
    unsigned short* Abf = (unsigned short*)(ws + (size_t)C_ROWS * D_DIM * 2);  // 1 MB
    float* part = (float*)(ws + (size_t)C_ROWS * D_DIM * 2 + (size_t)B_ROWS * D_DIM * 2);  // 1 MB
    float* rowloss = part + (size_t)B_ROWS * NBLK;                             // 4 KB

    norm_rows_kernel<<<(C_ROWS + B_ROWS) / 4, 256, 0, stream>>>(prox, emb, Pbf, Abf);
    gemm_lse_kernel<<<dim3(B_ROWS / 128, NBLK), 256, 0, stream>>>(Abf, Pbf, part);
    rowloss_kernel<<<B_ROWS / 4, 256, 0, stream>>>(part, Abf, Pbf, labels, rowloss);
    finalize_kernel<<<1, 256, 0, stream>>>(rowloss, out);
}